// Round 13
// baseline (606.772 us; speedup 1.0000x reference)
//
#include <hip/hip_runtime.h>
#include <hip/hip_fp16.h>

// Problem constants: B=64, N=256, F_IN=768, F_OUT=256
#define NB    64
#define NN    256
#define FIN   768
#define FOUT  256

typedef _Float16 half8v __attribute__((ext_vector_type(8)));
typedef float    float4v __attribute__((ext_vector_type(4)));

// f32 -> fp8 e4m3 (OCP, RNE) single value
__device__ inline unsigned char enc8(float v){
#if __has_builtin(__builtin_amdgcn_cvt_pk_fp8_f32)
  return (unsigned char)(__builtin_amdgcn_cvt_pk_fp8_f32(v, v, 0, false) & 0xFF);
#else
  float best = 1e30f; unsigned char bc = 0;
  for (int c = 0; c < 256; c++){
    if ((c & 0x7F) == 0x7F) continue;            // NaN codes
    int e = (c >> 3) & 15, mnt = c & 7;
    float mag = e ? ldexpf(1.f + mnt*0.125f, e-7) : ldexpf(mnt*0.125f, -6);
    float d = (c >> 7) ? -mag : mag;
    float err = fabsf(v - d);
    if (err < best){ best = err; bc = (unsigned char)c; }
  }
  return bc;
#endif
}

__device__ inline float4v mfma_fp8(long long a, long long b, float4v c){
  return __builtin_amdgcn_mfma_f32_16x16x32_fp8_fp8(a, b, c, 0, 0, 0);
}
__device__ inline float4v mfma_f16(half8v a, half8v b, float4v c){
  return __builtin_amdgcn_mfma_f32_16x16x32_f16(a, b, c, 0, 0, 0);
}

// Fast critical-path transcendentals (R20): both sit on the serial
// inter-barrier chain. rcp approx (~1ulp) + hw exp; error << fp8 noise.
__device__ inline float fsig(float x){
  return __builtin_amdgcn_rcpf(1.f + __expf(-x));
}
__device__ inline float ftanh(float x){
  const float xc = fminf(fmaxf(x, -9.f), 9.f);
  const float t  = __expf(2.f*xc);
  return (t - 1.f) * __builtin_amdgcn_rcpf(t + 1.f);
}

// ---------------------------------------------------------------------------
// setup: fused prep + quant + degmask (mutually independent; blockIdx roles).
// ---------------------------------------------------------------------------
__global__ __launch_bounds__(256) void setup_kernel(
    const float* __restrict__ emb_W, const float* __restrict__ ioux_W,
    const float* __restrict__ ioux_b, const float* __restrict__ coux_W,
    const float* __restrict__ coux_b,
    const float* __restrict__ iouh_W, const float* __restrict__ couh_W,
    const float* __restrict__ adj,
    _Float16* __restrict__ embW16, _Float16* __restrict__ Wcat16,
    float* __restrict__ biascat,
    unsigned char* __restrict__ iouh8, unsigned char* __restrict__ couh8,
    float* __restrict__ invrs_iou, float* __restrict__ invrs_cou,
    unsigned int* __restrict__ maskw, float* __restrict__ dinv)
{
  __shared__ float sm[256];               // quant reduction
  __shared__ unsigned int rb[256][8];     // degmask bit-transpose
  const int bid = blockIdx.x;
  const int t   = threadIdx.x;

  if (bid < 1539){
    // ---- prep role ----
    int idx = bid*256 + t;
    if (idx < 196608) { embW16[idx] = (_Float16)emb_W[idx]; return; }
    idx -= 196608;
    if (idx < 196608) {
      int o = idx >> 8, k = idx & 255;
      float v = (o < 512) ? ioux_W[o*256 + k] : coux_W[(o-512)*256 + k];
      Wcat16[idx] = (_Float16)v; return;
    }
    idx -= 196608;
    if (idx < 768) biascat[idx] = (idx < 512) ? ioux_b[idx] : coux_b[idx-512];
    return;
  }

  if (bid < 2307){
    // ---- quant role ----
    const int row = bid - 1539;           // 0..767
    const bool is_iou = (row < 512);
    const int rl = is_iou ? row : row - 512;
    const float w = is_iou ? iouh_W[(size_t)rl*256 + t] : couh_W[(size_t)rl*256 + t];
    sm[t] = fabsf(w);
    __syncthreads();
    for (int s = 128; s > 0; s >>= 1){
      if (t < s) sm[t] = fmaxf(sm[t], sm[t+s]);
      __syncthreads();
    }
    const float mx = sm[0];
    const float rs = (mx > 1e-20f) ? (240.0f / mx) : 1.0f;
    const unsigned char byte = enc8(w * rs);
    const int off = ((rl>>4)*8 + (t>>5))*512 + ((t>>3)&3)*128 + (rl&15)*8 + (t&7);
    if (is_iou) iouh8[off] = byte; else couh8[off] = byte;
    if (t == 0){
      const float inv = 1.0f / (rs * 16.0f);
      if (is_iou) invrs_iou[rl] = inv; else invrs_cou[rl] = inv;
    }
    return;
  }

  // ---- degmask role: one row-major read + LDS bit transpose ----
  {
    const int b = bid - 2307;
    const float* rowp = adj + (size_t)b*NN*NN + (size_t)t*NN;
    float s = 0.f;
    #pragma unroll
    for (int qc = 0; qc < 8; qc++){
      unsigned int w = 0;
      const float4* rp = (const float4*)(rowp + qc*32);
      #pragma unroll
      for (int j4 = 0; j4 < 8; j4++){
        float4 v = rp[j4];
        s += v.x + v.y + v.z + v.w;
        const int sh = j4*4;
        w |= (v.x != 0.f ? 1u : 0u) << sh;
        w |= (v.y != 0.f ? 1u : 0u) << (sh+1);
        w |= (v.z != 0.f ? 1u : 0u) << (sh+2);
        w |= (v.w != 0.f ? 1u : 0u) << (sh+3);
      }
      rb[t][qc] = w;
    }
    dinv[b*NN + t] = (s != 0.f) ? 1.0f/s : 0.0f;
    __syncthreads();
    #pragma unroll
    for (int qc = 0; qc < 8; qc++){
      unsigned int w = 0;
      #pragma unroll
      for (int jj = 0; jj < 32; jj++)
        w |= ((rb[qc*32 + jj][t>>5] >> (t&31)) & 1u) << jj;
      maskw[((size_t)b*NN + t)*8 + qc] = w;
    }
  }
}

// ---------------------------------------------------------------------------
// mid: fused {Hc = h @ embW^T} + {OUTX = Hc @ Wcat^T + bias} + {HcT slice}.
// (R19 structure, validated.)
// ---------------------------------------------------------------------------
__global__ __launch_bounds__(512) void mid_kernel(
    const float* __restrict__ h, const _Float16* __restrict__ embW16,
    const _Float16* __restrict__ Wcat16, const float* __restrict__ biascat,
    _Float16* __restrict__ Hc, _Float16* __restrict__ OUTX,
    _Float16* __restrict__ HcT)
{
  __shared__ _Float16 lds_hc[64][264];    // 64 rows x 256 cols (+8 pad)
  const int bx   = blockIdx.x;            // 0..255: rows [bx*64, +64)
  const int t    = threadIdx.x;           // 0..511
  const int wave = t >> 6;
  const int lane = t & 63;
  const int rgrp = wave & 3;              // row group of 16
  const int cseg = wave >> 2;             // 0/1: col segment
  const int m0g  = bx*64;
  const int mrow = m0g + rgrp*16 + (lane & 15);
  const int kgrp = lane >> 4;

  // ---- phase 1: Hc rows = h @ embW^T (cols cseg*128..+128) ----
  {
    float4v acc[8];
    #pragma unroll
    for (int nt = 0; nt < 8; nt++) acc[nt] = (float4v){0.f,0.f,0.f,0.f};
    for (int k0 = 0; k0 < FIN; k0 += 32){
      const int ka = k0 + kgrp*8;
      const float4* ap = (const float4*)(h + (size_t)mrow*FIN + ka);
      float4 a0 = ap[0], a1 = ap[1];
      half8v af;
      af[0]=(_Float16)a0.x; af[1]=(_Float16)a0.y; af[2]=(_Float16)a0.z; af[3]=(_Float16)a0.w;
      af[4]=(_Float16)a1.x; af[5]=(_Float16)a1.y; af[6]=(_Float16)a1.z; af[7]=(_Float16)a1.w;
      #pragma unroll
      for (int nt = 0; nt < 8; nt++){
        const int ncol = cseg*128 + nt*16 + (lane & 15);
        const half8v bf = *(const half8v*)(embW16 + (size_t)ncol*FIN + ka);
        acc[nt] = mfma_f16(af, bf, acc[nt]);
      }
    }
    #pragma unroll
    for (int nt = 0; nt < 8; nt++){
      const int ncol = cseg*128 + nt*16 + (lane & 15);
      #pragma unroll
      for (int r4 = 0; r4 < 4; r4++){
        const int ol = rgrp*16 + (lane>>4)*4 + r4;    // local row 0..63
        const _Float16 v = (_Float16)acc[nt][r4];
        lds_hc[ol][ncol] = v;
        Hc[(size_t)(m0g + ol)*FOUT + ncol] = v;
      }
    }
  }
  __syncthreads();

  // ---- phase 2: OUTX rows = HcTile(LDS) @ Wcat^T + bias ----
  {
    const int lrow = rgrp*16 + (lane & 15);
    #pragma unroll
    for (int pass = 0; pass < 3; pass++){
      const int oc0 = cseg*384 + pass*128;
      float4v acc[8];
      #pragma unroll
      for (int nt = 0; nt < 8; nt++) acc[nt] = (float4v){0.f,0.f,0.f,0.f};
      for (int k0 = 0; k0 < FOUT; k0 += 32){
        const int ka = k0 + kgrp*8;
        const half8v af = *(const half8v*)(&lds_hc[lrow][ka]);
        #pragma unroll
        for (int nt = 0; nt < 8; nt++){
          const int ncol = oc0 + nt*16 + (lane & 15);
          const half8v bf = *(const half8v*)(Wcat16 + (size_t)ncol*FOUT + ka);
          acc[nt] = mfma_f16(af, bf, acc[nt]);
        }
      }
      #pragma unroll
      for (int nt = 0; nt < 8; nt++){
        const int ncol = oc0 + nt*16 + (lane & 15);
        const float bv = biascat[ncol];
        #pragma unroll
        for (int r4 = 0; r4 < 4; r4++){
          const int orow = m0g + rgrp*16 + (lane>>4)*4 + r4;
          OUTX[(size_t)orow*768 + ncol] = (_Float16)(acc[nt][r4] + bv);
        }
      }
    }
  }

  // ---- phase 3: HcT[b][f][n-range] from LDS (64B contiguous per thread) ----
  {
    const int b  = bx >> 2;
    const int n0 = (bx & 3)*64;
    const int f  = t >> 1;        // 0..255
    const int ch = t & 1;         // half of 64 rows
    unsigned short buf[32];
    #pragma unroll
    for (int j = 0; j < 32; j++){
      union { _Float16 hv; unsigned short u; } cv;
      cv.hv = lds_hc[ch*32 + j][f];
      buf[j] = cv.u;
    }
    _Float16* dst = HcT + ((size_t)b*FOUT + f)*NN + n0 + ch*32;
    #pragma unroll
    for (int k = 0; k < 4; k++)
      *(uint4*)((char*)dst + k*16) = *(const uint4*)(&buf[k*8]);
  }
}

// ---------------------------------------------------------------------------
// scan R20 = R14 + critical-path cuts (latency-bound regime; MfmaUtil 11%):
//  1. fsig/ftanh (rcp+hw-exp) replace libm sigmoid/tanhf — both sit ON the
//     inter-barrier serial chain (sg -> p8 pre-B3; tanh -> dT consumed by
//     same wave's next-agg correction).
//  2. split-K accumulators: iou/cou dependent MFMA chains 8-deep -> 2x4-deep
//     (+24 VGPR; 120->~150 < 256 budget — R16's spill came from its
//     cross-loop pipeline state, not the split itself).
//  3. post-barrier LDS operand hoists (xp32[o1], z, xpv) so their ~120cyc
//     latency overlaps the MFMA chains.
// Everything else identical to R14 (proven 390 us).
// ---------------------------------------------------------------------------
#define OFF_BT   0
#define OFF_DT   33280
#define OFF_HNT  53760
#define OFF_XP32 74240
#define OFF_XP8  75264
#define OFF_P8   75520
#define OFF_Z    75776
#define OFF_PM   76800
#define OFF_MASK 77824
#define OFF_DINV 86016
#define SCAN_LDS 87040

__global__ __launch_bounds__(512, 2)
void scan_kernel(
    const _Float16* __restrict__ Hc,    // [B*N][256] f16 = h_e (row-major)
    const _Float16* __restrict__ HcT,   // [B][256 feat][256 node] f16
    const _Float16* __restrict__ OUTX,  // [B*N][768] f16: [iou_x ; cou_x]
    const unsigned char* __restrict__ iouh8,  // swizzled fp8 [512][256]
    const unsigned char* __restrict__ couh8,  // swizzled fp8 [256][256]
    const float* __restrict__ invrs_iou,      // [512]
    const float* __restrict__ invrs_cou,      // [256]
    const float* __restrict__ dinv,     // [B*N]
    const unsigned int* __restrict__ maskw, // [B*N][8]
    const float* __restrict__ iouh_b,   // [512]
    const float* __restrict__ couh_b,   // [256]
    const float* __restrict__ fc_W,     // [2][256]
    const float* __restrict__ fc_b,     // [2]
    float* __restrict__ out)            // [B][2]
{
  const int b    = blockIdx.x;
  const int t    = threadIdx.x;        // 0..511
  const int wave = t >> 6;             // 0..7
  const int lane = t & 63;
  const int q    = lane >> 4;          // k-octet within MFMA frags
  const int r    = lane & 15;          // row/col index within MFMA tile
  const int f0   = 32*wave;            // wave's feature-slice base

  extern __shared__ __align__(16) char smem[];
  float*         sh_xp32 = (float*)(smem + OFF_XP32);
  unsigned char* sh_xp8  = (unsigned char*)(smem + OFF_XP8);
  unsigned char* sh_p8   = (unsigned char*)(smem + OFF_P8);
  float*         sh_z    = (float*)(smem + OFF_Z);
  float*         sh_pm   = (float*)(smem + OFF_PM);
  unsigned int*  sh_mask = (unsigned int*)(smem + OFF_MASK);
  float*         sh_dinv = (float*)(smem + OFF_DINV);

  // ---- one-time staging: zero delta-tile (5120 dw), mask words, dinv ----
  #pragma unroll
  for (int k = 0; k < 10; k++)
    ((unsigned int*)(smem + OFF_DT))[k*512 + t] = 0u;
  {
    const unsigned int* mg = maskw + ((size_t)b*NN)*8;
    #pragma unroll
    for (int k = 0; k < 4; k++) sh_mask[k*512 + t] = mg[k*512 + t];
    if (t < 256) sh_dinv[t] = dinv[(size_t)b*NN + t];
  }

  // ---- Hreg[g][ks]: H^T[f0+16g+r][ks*32 + q*8 + e] (64 VGPR) ----
  half8v Hreg[2][8];
  #pragma unroll
  for (int g = 0; g < 2; g++){
    const _Float16* hp = HcT + ((size_t)b*FOUT + f0 + 16*g + r)*NN + q*8;
    #pragma unroll
    for (int ks = 0; ks < 8; ks++)
      Hreg[g][ks] = *(const half8v*)(hp + ks*32);
  }

  // ---- recurrent weight frags (loop-invariant; 64+32 VGPR) ----
  long long ifrag[4][8];
  #pragma unroll
  for (int tt = 0; tt < 4; tt++)
    #pragma unroll
    for (int kc = 0; kc < 8; kc++)
      ifrag[tt][kc] = *(const long long*)(iouh8 + (size_t)(((4*wave+tt)*8 + kc)*512) + q*128 + r*8);
  long long cfrag[2][8];
  #pragma unroll
  for (int tt = 0; tt < 2; tt++)
    #pragma unroll
    for (int kc = 0; kc < 8; kc++)
      cfrag[tt][kc] = *(const long long*)(couh8 + (size_t)(((2*wave+tt)*8 + kc)*512) + q*128 + r*8);

  // ---- per-lane output assignments ----
  const int o1    = 64*wave + 16*(r>>2) + q*4 + (r&3);       // iou: 1/lane
  const int o_upd = 32*wave + 16*((r>>2)&1) + q*4 + (r&3);   // cou: lanes r<8
  const float bi1 = iouh_b[o1];
  const float vi1 = invrs_iou[o1];
  const float bcou_l = couh_b[o_upd];
  const float invc_l = invrs_cou[o_upd];
  float pmax = -1e30f;

  __syncthreads();   // staging done
  unsigned int wl_cur = sh_mask[0];

  #pragma unroll 1
  for (int i = 0; i < NN; i++){
    const size_t row = (size_t)b*NN + i;

    // ======== tile boundary (no barrier: all edges same-wave) ========
    if ((i & 31) == 0){
      const int tile = i >> 5;
      if (tile > 0){
        const int tprev = tile - 1;
        #pragma unroll
        for (int g = 0; g < 2; g++){
          const half8v hv = *(const half8v*)(smem + OFF_HNT + (f0 + 16*g + r)*80 + q*16);
          #pragma unroll
          for (int ks = 0; ks < 8; ks++) if (ks == tprev) Hreg[g][ks] = hv;
        }
      }
      float4v bacc[2][2];
      #pragma unroll
      for (int rt = 0; rt < 2; rt++)
        #pragma unroll
        for (int g = 0; g < 2; g++) bacc[rt][g] = (float4v){0.f,0.f,0.f,0.f};
      #pragma unroll
      for (int rt = 0; rt < 2; rt++){
        #pragma unroll
        for (int ks = 0; ks < 8; ks++){
          const unsigned int wm = sh_mask[(i + rt*16 + r)*8 + ks];
          half8v am;
          #pragma unroll
          for (int e = 0; e < 8; e++)
            am[e] = (_Float16)((wm >> (q*8 + e)) & 1u);
          bacc[rt][0] = mfma_f16(am, Hreg[0][ks], bacc[rt][0]);
          bacc[rt][1] = mfma_f16(am, Hreg[1][ks], bacc[rt][1]);
        }
      }
      #pragma unroll
      for (int rt = 0; rt < 2; rt++)
        #pragma unroll
        for (int g = 0; g < 2; g++)
          #pragma unroll
          for (int jj = 0; jj < 4; jj++)
            *(float*)(smem + (rt*16 + q*4 + jj)*1040 + (f0 + 16*g + r)*4) = bacc[rt][g][jj];
    }
    // ================================================================

    const int li = i & 31;
    const unsigned int wl_next = sh_mask[((i+1)&255)*8 + (((i+1)>>5)&7)];
    const float oxi = (float)OUTX[row*768 + o1];
    const float oxc = (float)OUTX[row*768 + 512 + o_upd];
    const float he  = (float)Hc[row*FOUT + o_upd];
    const float dv  = sh_dinv[i];

    // ---- agg: 2 K=32 correction MFMAs + B_tile (all same-wave inputs) ----
    {
      const unsigned int wl = wl_cur & ((1u << li) - 1u);  // li==0 -> 0
      half8v af;
      #pragma unroll
      for (int e = 0; e < 8; e++)
        af[e] = (_Float16)((wl >> (q*8 + e)) & 1u);
      #pragma unroll
      for (int g = 0; g < 2; g++){
        const int fg = f0 + 16*g + r;
        const half8v bf = *(const half8v*)(smem + OFF_DT + fg*80 + q*16);
        float4v ag = (float4v){0.f,0.f,0.f,0.f};
        ag = mfma_f16(af, bf, ag);
        const float bt = *(const float*)(smem + li*1040 + fg*4);
        const float xp = (bt + ag[0]) * dv;
        if (q == 0)      sh_xp32[fg] = xp;
        else if (q == 1) sh_xp8[fg] = enc8(xp * 16.f);
      }
    }
    wl_cur = wl_next;
    __syncthreads();                                    // B2 (xp cross-wave)

    // ---- iou matvec: 32 fp8 MFMAs as 2x4-deep chains, 1 sigmoid/lane ----
    {
      const float x1pre = sh_xp32[o1];   // hoisted: overlaps MFMA chains
      float4v iacc[4], iacc2[4];
      #pragma unroll
      for (int tt = 0; tt < 4; tt++){
        iacc[tt]  = (float4v){0.f,0.f,0.f,0.f};
        iacc2[tt] = (float4v){0.f,0.f,0.f,0.f};
      }
      #pragma unroll
      for (int kc = 0; kc < 4; kc++){
        const long long blo = *(const long long*)(sh_xp8 + kc*32 + q*8);
        const long long bhi = *(const long long*)(sh_xp8 + (kc+4)*32 + q*8);
        #pragma unroll
        for (int tt = 0; tt < 4; tt++){
          iacc[tt]  = mfma_fp8(ifrag[tt][kc],   blo, iacc[tt]);
          iacc2[tt] = mfma_fp8(ifrag[tt][kc+4], bhi, iacc2[tt]);
        }
      }
      float d1 = 0.f;
      #pragma unroll
      for (int tt = 0; tt < 4; tt++) if ((r>>2) == tt){
        #pragma unroll
        for (int jj = 0; jj < 4; jj++) if ((r&3) == jj)
          d1 = iacc[tt][jj] + iacc2[tt][jj];
      }
      const float g1 = d1*vi1 + oxi + bi1;
      const float sg = fsig(g1);
      if (wave < 4) sh_p8[o1] = enc8(sg * x1pre * 16.f);   // r-gates
      else          sh_z[o1 - 256] = sg;                   // z-gates
    }
    __syncthreads();                                    // B3 (p8/z cross-wave)

    // ---- cou matvec: 16 fp8 MFMAs as 2x4-deep + fused update (r<8) ----
    {
      const float z_pre   = sh_z[o_upd];     // hoisted
      const float xpv_pre = sh_xp32[o_upd];  // hoisted
      float4v cacc[2], cacc2[2];
      #pragma unroll
      for (int tt = 0; tt < 2; tt++){
        cacc[tt]  = (float4v){0.f,0.f,0.f,0.f};
        cacc2[tt] = (float4v){0.f,0.f,0.f,0.f};
      }
      #pragma unroll
      for (int kc = 0; kc < 4; kc++){
        const long long blo = *(const long long*)(sh_p8 + kc*32 + q*8);
        const long long bhi = *(const long long*)(sh_p8 + (kc+4)*32 + q*8);
        #pragma unroll
        for (int tt = 0; tt < 2; tt++){
          cacc[tt]  = mfma_fp8(cfrag[tt][kc],   blo, cacc[tt]);
          cacc2[tt] = mfma_fp8(cfrag[tt][kc+4], bhi, cacc2[tt]);
        }
      }
      if (r < 8){
        float cd = 0.f;
        #pragma unroll
        for (int tt = 0; tt < 2; tt++) if ((r>>2) == tt){
          #pragma unroll
          for (int jj = 0; jj < 4; jj++) if ((r&3) == jj)
            cd = cacc[tt][jj] + cacc2[tt][jj];
        }
        const float v   = cd*invc_l + oxc + bcou_l;
        const float hcv = ftanh(v);
        const float hn  = z_pre*xpv_pre + (1.f - z_pre)*hcv;
        pmax = fmaxf(pmax, hn);
        *(_Float16*)(smem + OFF_DT  + o_upd*80 + li*2) = (_Float16)(hn - he);
        *(_Float16*)(smem + OFF_HNT + o_upd*80 + li*2) = (_Float16)hn;
      }
    }
    // no B4: dT/hnT consumed same-wave; xp/p8/z overwrites fenced by B2/B3
  }

  // ---- epilogue: pooled max -> fc ----
  if (r < 8) sh_pm[o_upd] = pmax;
  __syncthreads();
  if (t < 128){
    const int c = t >> 6;   // 0 or 1
    float s = 0.f;
    #pragma unroll
    for (int qq = 0; qq < 4; qq++){
      const int f = (t & 63) + qq*64;
      s += fc_W[c*256 + f] * sh_pm[f];
    }
    #pragma unroll
    for (int off = 32; off > 0; off >>= 1) s += __shfl_xor(s, off, 64);
    if ((t & 63) == 0) out[b*2 + c] = s + fc_b[c];
  }
}

// ---------------------------------------------------------------------------
extern "C" void kernel_launch(void* const* d_in, const int* in_sizes, int n_in,
                              void* d_out, int out_size, void* d_ws, size_t ws_size,
                              hipStream_t stream)
{
  (void)in_sizes; (void)n_in; (void)out_size; (void)ws_size;
  const float* h      = (const float*)d_in[0];
  const float* adj    = (const float*)d_in[1];
  const float* emb_W  = (const float*)d_in[2];
  const float* ioux_W = (const float*)d_in[3];
  const float* ioux_b = (const float*)d_in[4];
  const float* iouh_W = (const float*)d_in[5];
  const float* iouh_b = (const float*)d_in[6];
  const float* coux_W = (const float*)d_in[7];
  const float* coux_b = (const float*)d_in[8];
  const float* couh_W = (const float*)d_in[9];
  const float* couh_b = (const float*)d_in[10];
  const float* fc_W   = (const float*)d_in[11];
  const float* fc_b   = (const float*)d_in[12];
  float* out = (float*)d_out;

  // ---- carve workspace (256B aligned chunks) ----
  size_t off = 0;
  char* base = (char*)d_ws;
  auto carve = [&](size_t bytes)->char* {
    off = (off + 255) & ~(size_t)255;
    char* p = base + off;
    off += bytes;
    return p;
  };
  _Float16* embW16 = (_Float16*)carve((size_t)256*768*2);
  _Float16* Wcat16 = (_Float16*)carve((size_t)768*256*2);
  float*    biascat= (float*)  carve((size_t)768*4);
  unsigned char* iouh8 = (unsigned char*)carve(131072);
  unsigned char* couh8 = (unsigned char*)carve(65536);
  float*    invrs_iou = (float*)carve(512*4);
  float*    invrs_cou = (float*)carve(256*4);
  float*    dinv   = (float*)  carve((size_t)NB*NN*4);
  unsigned int* maskw = (unsigned int*)carve((size_t)NB*NN*8*4 + 64); // +pad
  _Float16* Hc     = (_Float16*)carve((size_t)NB*NN*FOUT*2);       // h_e
  _Float16* HcT    = (_Float16*)carve((size_t)NB*NN*FOUT*2);       // h_e^T
  _Float16* OUTX   = (_Float16*)carve((size_t)NB*NN*768*2);        // [iou_x;cou_x]

  // raise dynamic LDS cap for the scan kernel (idempotent, non-stream op)
  hipFuncSetAttribute((const void*)scan_kernel,
                      hipFuncAttributeMaxDynamicSharedMemorySize, SCAN_LDS);

  // 1) fused setup: prep + quant + degmask (independent, one launch)
  setup_kernel<<<dim3(2371), dim3(256), 0, stream>>>(
      emb_W, ioux_W, ioux_b, coux_W, coux_b, iouh_W, couh_W, adj,
      embW16, Wcat16, biascat, iouh8, couh8, invrs_iou, invrs_cou,
      maskw, dinv);

  // 2) fused mid: Hc GEMM + OUTX GEMM (from LDS) + HcT transpose
  mid_kernel<<<dim3(256), dim3(512), 0, stream>>>(
      h, embW16, Wcat16, biascat, Hc, OUTX, HcT);

  // 3) sequential tree scan (R20: critical-path cuts on R14 structure)
  scan_kernel<<<dim3(NB), dim3(512), SCAN_LDS, stream>>>(
      Hc, HcT, OUTX, iouh8, couh8, invrs_iou, invrs_cou, dinv, maskw,
      iouh_b, couh_b, fc_W, fc_b, out);
}